// Round 5
// baseline (737.982 us; speedup 1.0000x reference)
//
#include <hip/hip_runtime.h>
#include <stdint.h>

// ---------- bf16 helpers (OCP bf16 == high 16 bits of f32) ----------
__device__ __forceinline__ float bf2f(unsigned short h) {
  union { uint32_t u; float f; } v; v.u = ((uint32_t)h) << 16; return v.f;
}
__device__ __forceinline__ unsigned short f2bf(float f) {
  union { float f; uint32_t u; } v; v.f = f;
  uint32_t u = v.u;
  u += 0x7FFFu + ((u >> 16) & 1u);   // round-to-nearest-even
  return (unsigned short)(u >> 16);
}
__device__ __forceinline__ uint32_t pack2bf(float a, float b) {
  return (uint32_t)f2bf(a) | ((uint32_t)f2bf(b) << 16);
}
// raw-dtype readers (probed at runtime)
__device__ __forceinline__ int ld_idx(const void* p, size_t i, int is64) {
  return is64 ? (int)((const long long*)p)[i] : ((const int*)p)[i];
}
__device__ __forceinline__ float ld_w(const void* p, size_t i, int f32) {
  return f32 ? ((const float*)p)[i] : bf2f(((const unsigned short*)p)[i]);
}

typedef __attribute__((ext_vector_type(8))) short short8;   // 8 bf16 (4 VGPRs)
typedef __attribute__((ext_vector_type(4))) float floatx4;  // MFMA C/D

// async global->LDS, 16 B/lane. LDS dest = wave-uniform base + lane*16 (m104/m108).
__device__ __forceinline__ void gl2lds16(const unsigned short* g, unsigned short* l) {
  __builtin_amdgcn_global_load_lds(
      (const __attribute__((address_space(1))) uint32_t*)(const void*)g,
      (__attribute__((address_space(3))) uint32_t*)(void*)l,
      16, 0, 0);
}

// ---------- init + dtype probe (merged; probe is wave-parallel in block 0) ----------
__global__ void bgcn_init_probe(float* __restrict__ deg, int* __restrict__ counts,
                                int* __restrict__ fill, int n,
                                const uint32_t* __restrict__ xw,
                                const uint32_t* __restrict__ iw,
                                int* __restrict__ flags) {
  int i = blockIdx.x * 256 + threadIdx.x;
  if (i < n) { deg[i] = 1.0f; counts[i] = 0; fill[i] = 0; }
  if (blockIdx.x == 0 && threadIdx.x < 64) {
    int lane = threadIdx.x;
    // X dtype heuristic: 256 exponent bytes, 4 per lane (parallel loads)
    int hits = 0;
    #pragma unroll
    for (int j = 0; j < 4; ++j) {
      uint32_t b = (xw[lane * 4 + j] >> 8) & 0x7F;
      hits += (b >= 0x38 && b <= 0x41) ? 1 : 0;
    }
    #pragma unroll
    for (int off = 32; off; off >>= 1) hits += __shfl_xor(hits, off);
    // index dtype: odd 32-bit words 1,3,...,127 all zero => int64
    unsigned long long nz = __ballot(iw[2 * lane + 1] != 0u);
    if (lane == 0) {
      flags[0] = (hits < 128) ? 1 : 0;   // 1 => fp32 floats
      flags[1] = (nz == 0ull) ? 1 : 0;   // 1 => int64 indices
    }
  }
}

// ---------- canonicalization ----------
// X pre-pass, 8 elem/thread
__global__ void bgcn_cvt8(const void* __restrict__ src, unsigned short* __restrict__ dst,
                          int n8, const int* __restrict__ flags) {
  int i = blockIdx.x * 256 + threadIdx.x;
  if (i >= n8) return;
  size_t o = (size_t)i * 8;
  uint4 d;
  if (flags[0]) {
    const float4* f = (const float4*)((const float*)src + o);
    float4 f0 = f[0], f1 = f[1];
    d = make_uint4(pack2bf(f0.x, f0.y), pack2bf(f0.z, f0.w),
                   pack2bf(f1.x, f1.y), pack2bf(f1.z, f1.w));
  } else {
    d = *(const uint4*)((const unsigned short*)src + o);
  }
  *(uint4*)(dst + o) = d;
}

// merged weight canonicalization: one kernel, 586 blocks.
//  blocks [0,512): W1 transpose-cvt  (K=1024, N=512) -> W1t[512][1024]
//  blocks [512,576): W2 transpose-cvt (K=512, N=128) -> W2t[128][512]
//  blocks [576,586): small tensors b1/b2/Wfc/bfc
__device__ __forceinline__ void cvt_t_tile(const void* src, unsigned short* dst,
                                           int K, int N, int k0, int n0, bool f32,
                                           unsigned short (*tile)[33]) {
  int tx = threadIdx.x & 31, ty = threadIdx.x >> 5;   // ty 0..7
  #pragma unroll
  for (int i = 0; i < 4; ++i) {
    size_t s = (size_t)(k0 + ty + i * 8) * N + n0 + tx;
    tile[ty + i * 8][tx] = f32 ? f2bf(((const float*)src)[s])
                               : ((const unsigned short*)src)[s];
  }
  __syncthreads();
  #pragma unroll
  for (int i = 0; i < 4; ++i)
    dst[(size_t)(n0 + ty + i * 8) * K + k0 + tx] = tile[tx][ty + i * 8];
}
__global__ __launch_bounds__(256) void bgcn_cvt_weights(
    const void* __restrict__ w1, const void* __restrict__ w2,
    const void* b1, const void* b2, const void* wfc, const void* bfc,
    unsigned short* __restrict__ W1t, unsigned short* __restrict__ W2t,
    unsigned short* db1, unsigned short* db2,
    unsigned short* dwfc, unsigned short* dbfc,
    const int* __restrict__ flags) {
  __shared__ unsigned short tile[32][33];
  bool f32 = flags[0];
  int b = blockIdx.x;
  if (b < 512) {
    cvt_t_tile(w1, W1t, 1024, 512, (b >> 4) * 32, (b & 15) * 32, f32, tile);
  } else if (b < 576) {
    int b2i = b - 512;
    cvt_t_tile(w2, W2t, 512, 128, (b2i >> 2) * 32, (b2i & 3) * 32, f32, tile);
  } else {
    int i = (b - 576) * 256 + threadIdx.x;
    const void* s; unsigned short* d; int j;
    if (i < 512)            { s = b1;  d = db1;  j = i; }
    else if (i < 640)       { s = b2;  d = db2;  j = i - 512; }
    else if (i < 2432)      { s = wfc; d = dwfc; j = i - 640; }
    else if (i < 2446)      { s = bfc; d = dbfc; j = i - 2432; }
    else return;
    d[j] = f32 ? f2bf(((const float*)s)[j]) : ((const unsigned short*)s)[j];
  }
}

// ---------- graph preprocessing ----------
__global__ void bgcn_deg_hist(const void* __restrict__ ei, const void* __restrict__ ew,
                              const int* __restrict__ flags,
                              float* __restrict__ deg, int* __restrict__ counts, int E) {
  int e = blockIdx.x * 256 + threadIdx.x;
  if (e >= E) return;
  int c = ld_idx(ei, (size_t)E + e, flags[1]);
  atomicAdd(&deg[c], ld_w(ew, e, flags[0]));
  atomicAdd(&counts[c], 1);
}
// block scan over counts -> rowptr (inclusive partials); also finalizes dis
__global__ void bgcn_scan_block(const int* __restrict__ counts, int* __restrict__ rowptr,
                                int* __restrict__ blocksum,
                                const float* __restrict__ deg, float* __restrict__ dis,
                                int n) {
  __shared__ int buf[1024];
  int gid = blockIdx.x * 1024 + threadIdx.x;
  int v = (gid < n) ? counts[gid] : 0;
  buf[threadIdx.x] = v;
  __syncthreads();
  for (int off = 1; off < 1024; off <<= 1) {
    int x = (threadIdx.x >= off) ? buf[threadIdx.x - off] : 0;
    __syncthreads();
    buf[threadIdx.x] += x;
    __syncthreads();
  }
  if (gid < n) {
    rowptr[gid + 1] = buf[threadIdx.x];
    dis[gid] = rsqrtf(deg[gid]);   // deg final here (after deg_hist)
  }
  if (threadIdx.x == 1023) blocksum[blockIdx.x] = buf[1023];
}
// block-parallel exclusive scan of blocksum (nb <= 1024)
__global__ void bgcn_scan_tops(int* __restrict__ blocksum, int nb) {
  __shared__ int buf[1024];
  int t = threadIdx.x;
  int v = (t < nb) ? blocksum[t] : 0;
  buf[t] = v;
  __syncthreads();
  for (int off = 1; off < 1024; off <<= 1) {
    int x = (t >= off) ? buf[t - off] : 0;
    __syncthreads();
    buf[t] += x;
    __syncthreads();
  }
  if (t < nb) blocksum[t] = buf[t] - v;   // exclusive
}
__global__ void bgcn_scan_add(int* __restrict__ rowptr, const int* __restrict__ blocksum, int n) {
  int gid = blockIdx.x * 1024 + threadIdx.x;
  if (gid < n) rowptr[gid + 1] += blocksum[blockIdx.x];
  if (gid == 0) rowptr[0] = 0;
}
// scatter into CSR; (src, norm) packed as one int2 -> single 8B scattered store
__global__ void bgcn_scatter(const void* __restrict__ ei, const void* __restrict__ ew,
                             const int* __restrict__ flags,
                             const float* __restrict__ dis,
                             const int* __restrict__ rowptr, int* __restrict__ fill,
                             int2* __restrict__ epair, int E) {
  int e = blockIdx.x * 256 + threadIdx.x;
  if (e >= E) return;
  int is64 = flags[1];
  int r = ld_idx(ei, e, is64), c = ld_idx(ei, (size_t)E + e, is64);
  int pos = rowptr[c] + atomicAdd(&fill[c], 1);
  float nrm = dis[r] * ld_w(ew, e, flags[0]) * dis[c];
  epair[pos] = make_int2(r, __float_as_int(nrm));
}

// ---------- m97-style MFMA GEMM (bf16 A): C[MxN] = A[MxK] @ Bt[NxK]^T ----------
__global__ __launch_bounds__(256) void bgcn_gemm_lds(
    const unsigned short* __restrict__ A,
    const unsigned short* __restrict__ Bt,
    unsigned short* __restrict__ C,
    int M, int N, int K, int nblk_bits) {
  __shared__ unsigned short Abuf[128 * 32];
  __shared__ unsigned short Bbuf[128 * 32];
  int t = threadIdx.x;
  int wave = t >> 6, lane = t & 63;
  int bx = blockIdx.x;
  int nblk = bx & ((1 << nblk_bits) - 1);
  int mblk = bx >> nblk_bits;
  int m0 = mblk * 128, n0 = nblk * 128;

  floatx4 acc[4][4];
  #pragma unroll
  for (int i = 0; i < 4; ++i)
    #pragma unroll
    for (int j = 0; j < 4; ++j)
      #pragma unroll
      for (int r = 0; r < 4; ++r) acc[i][j][r] = 0.0f;

  int rii  = lane >> 2;
  int koff = (lane & 3) * 8;
  int ar0 = m0 + wave * 32 + rii;      if (ar0 >= M) ar0 = M - 1;
  int ar1 = m0 + wave * 32 + 16 + rii; if (ar1 >= M) ar1 = M - 1;
  const unsigned short* Ag0 = A + (size_t)ar0 * K + koff;
  const unsigned short* Ag1 = A + (size_t)ar1 * K + koff;
  const unsigned short* Bg0 = Bt + (size_t)(n0 + wave * 32 + rii) * K + koff;
  const unsigned short* Bg1 = Bg0 + (size_t)16 * K;
  unsigned short* Al0 = Abuf + (wave * 32) * 32 + lane * 8;
  unsigned short* Al1 = Abuf + (wave * 32 + 16) * 32 + lane * 8;
  unsigned short* Bl0 = Bbuf + (wave * 32) * 32 + lane * 8;
  unsigned short* Bl1 = Bbuf + (wave * 32 + 16) * 32 + lane * 8;

  int fr = lane & 15;
  int fk = (lane >> 4) * 8;
  int mw = (wave & 1) * 64;
  int nw = (wave >> 1) * 64;

  for (int k0 = 0; k0 < K; k0 += 32) {
    gl2lds16(Ag0 + k0, Al0);
    gl2lds16(Ag1 + k0, Al1);
    gl2lds16(Bg0 + k0, Bl0);
    gl2lds16(Bg1 + k0, Bl1);
    __syncthreads();

    short8 afr[4], bfr[4];
    #pragma unroll
    for (int i = 0; i < 4; ++i)
      afr[i] = *(const short8*)(Abuf + (mw + i * 16 + fr) * 32 + fk);
    #pragma unroll
    for (int i = 0; i < 4; ++i)
      bfr[i] = *(const short8*)(Bbuf + (nw + i * 16 + fr) * 32 + fk);
    #pragma unroll
    for (int mt = 0; mt < 4; ++mt)
      #pragma unroll
      for (int nt = 0; nt < 4; ++nt)
        acc[mt][nt] = __builtin_amdgcn_mfma_f32_16x16x32_bf16(afr[mt], bfr[nt], acc[mt][nt], 0, 0, 0);
    __syncthreads();
  }

  int col_l = lane & 15;
  int row_b = (lane >> 4) * 4;
  #pragma unroll
  for (int mt = 0; mt < 4; ++mt)
    #pragma unroll
    for (int nt = 0; nt < 4; ++nt)
      #pragma unroll
      for (int r = 0; r < 4; ++r) {
        int m = m0 + mw + mt * 16 + row_b + r;
        if (m < M)
          C[(size_t)m * N + n0 + nw + nt * 16 + col_l] = f2bf(acc[mt][nt][r]);
      }
}

// ---------- fallback GEMM (fp32-or-bf16 A via VGPR staging) ----------
#define GST 40
__global__ __launch_bounds__(256, 2) void bgcn_gemm128(
    const void* __restrict__ Araw, int a_probe, const int* __restrict__ flags,
    const unsigned short* __restrict__ Bt,
    unsigned short* __restrict__ C,
    int M, int N, int K, int nblk_bits) {
  __shared__ unsigned short Abuf[128 * GST];
  __shared__ unsigned short Bbuf[128 * GST];
  const bool a_fp32 = a_probe && flags[0];
  int t = threadIdx.x;
  int wave = t >> 6, lane = t & 63;
  int bx = blockIdx.x;
  int nblk = bx & ((1 << nblk_bits) - 1);
  int mblk = bx >> nblk_bits;
  int m0 = mblk * 128, n0 = nblk * 128;

  floatx4 acc[4][4];
  #pragma unroll
  for (int i = 0; i < 4; ++i)
    #pragma unroll
    for (int j = 0; j < 4; ++j)
      #pragma unroll
      for (int r = 0; r < 4; ++r) acc[i][j][r] = 0.0f;

  int srow  = t >> 1;
  int skoff = (t & 1) * 16;
  int am = m0 + srow; if (am >= M) am = M - 1;
  const float*          Af = (const float*)Araw          + (size_t)am * K + skoff;
  const unsigned short* Ah = (const unsigned short*)Araw + (size_t)am * K + skoff;
  const unsigned short* Bp = Bt + (size_t)(n0 + srow) * K + skoff;
  unsigned short* AL = Abuf + srow * GST + skoff;
  unsigned short* BL = Bbuf + srow * GST + skoff;

  int fr = lane & 15;
  int fk = (lane >> 4) * 8;
  int mw = (wave & 1) * 64;
  int nw = (wave >> 1) * 64;

  for (int k0 = 0; k0 < K; k0 += 32) {
    uint4 a0, a1;
    if (a_fp32) {
      float4 f0 = *(const float4*)(Af + k0);
      float4 f1 = *(const float4*)(Af + k0 + 4);
      float4 f2 = *(const float4*)(Af + k0 + 8);
      float4 f3 = *(const float4*)(Af + k0 + 12);
      a0 = make_uint4(pack2bf(f0.x, f0.y), pack2bf(f0.z, f0.w),
                      pack2bf(f1.x, f1.y), pack2bf(f1.z, f1.w));
      a1 = make_uint4(pack2bf(f2.x, f2.y), pack2bf(f2.z, f2.w),
                      pack2bf(f3.x, f3.y), pack2bf(f3.z, f3.w));
    } else {
      a0 = *(const uint4*)(Ah + k0);
      a1 = *(const uint4*)(Ah + k0 + 8);
    }
    uint4 b0 = *(const uint4*)(Bp + k0);
    uint4 b1 = *(const uint4*)(Bp + k0 + 8);
    *(uint4*)AL       = a0;
    *(uint4*)(AL + 8) = a1;
    *(uint4*)BL       = b0;
    *(uint4*)(BL + 8) = b1;
    __syncthreads();

    short8 afr[4], bfr[4];
    #pragma unroll
    for (int i = 0; i < 4; ++i)
      afr[i] = *(const short8*)(Abuf + (mw + i * 16 + fr) * GST + fk);
    #pragma unroll
    for (int i = 0; i < 4; ++i)
      bfr[i] = *(const short8*)(Bbuf + (nw + i * 16 + fr) * GST + fk);
    #pragma unroll
    for (int mt = 0; mt < 4; ++mt)
      #pragma unroll
      for (int nt = 0; nt < 4; ++nt)
        acc[mt][nt] = __builtin_amdgcn_mfma_f32_16x16x32_bf16(afr[mt], bfr[nt], acc[mt][nt], 0, 0, 0);
    __syncthreads();
  }

  int col_l = lane & 15;
  int row_b = (lane >> 4) * 4;
  #pragma unroll
  for (int mt = 0; mt < 4; ++mt)
    #pragma unroll
    for (int nt = 0; nt < 4; ++nt)
      #pragma unroll
      for (int r = 0; r < 4; ++r) {
        int m = m0 + mw + mt * 16 + row_b + r;
        if (m < M)
          C[(size_t)m * N + n0 + nw + nt * 16 + col_l] = f2bf(acc[mt][nt][r]);
      }
}

// ---------- aggregation: out[c] = sum_e norm*H[src] + (1/deg_c)*H[c] + b, relu ----------
// DEPTH=8 keeps pipeline VGPR state under the 64-VGPR occupancy step.
// FUSE_FC (F=128, WPN=1): 128->14 matvec + sigmoid in the epilogue.
//   Wfc staged in LDS o-major (Ws[o][k], float2/lane reads, ~conflict-free);
//   wave butterfly-reduce; lane 0 stores 14 f32. Kills the X3 round-trip.
__device__ __forceinline__ void accum4(float* acc, uint2 r, float w) {
  acc[0] += w * bf2f((unsigned short)(r.x & 0xffff));
  acc[1] += w * bf2f((unsigned short)(r.x >> 16));
  acc[2] += w * bf2f((unsigned short)(r.y & 0xffff));
  acc[3] += w * bf2f((unsigned short)(r.y >> 16));
}
__device__ __forceinline__ void accum2(float* acc, uint32_t r, float w) {
  acc[0] += w * bf2f((unsigned short)(r & 0xffff));
  acc[1] += w * bf2f((unsigned short)(r >> 16));
}

template <int F, int WPN, bool FUSE_FC>
__global__ __launch_bounds__(256) void bgcn_aggregate(
    const unsigned short* __restrict__ H,
    const int* __restrict__ rowptr,
    const int2* __restrict__ epair,
    const float* __restrict__ dis,
    const unsigned short* __restrict__ bias,
    unsigned short* __restrict__ Out,
    const unsigned short* __restrict__ Wfc,   // [128][14] bf16 (FUSE_FC)
    const unsigned short* __restrict__ bfc,   // [14] bf16     (FUSE_FC)
    float* __restrict__ fcout,                // [N][14] f32   (FUSE_FC)
    int n_nodes) {
  constexpr int FPW = F / WPN;     // features per wave: 256 | 128
  constexpr int VPL = FPW / 64;    // bf16 elems per lane: 4 | 2
  constexpr int NPB = 4 / WPN;     // nodes per block:   2   | 4
  constexpr int DEPTH = 8;         // gather loads in flight

  __shared__ float Ws[FUSE_FC ? 14 * 128 : 1];   // o-major: Ws[o*128 + k]
  __shared__ float bs[FUSE_FC ? 16 : 1];
  if constexpr (FUSE_FC) {
    for (int i = threadIdx.x; i < 14 * 128; i += 256) {
      int k = i / 14, o = i % 14;                 // Wfc is k-major [128][14]
      Ws[o * 128 + k] = bf2f(Wfc[i]);
    }
    if (threadIdx.x < 14) bs[threadIdx.x] = bf2f(bfc[threadIdx.x]);
    __syncthreads();
  }

  int t = threadIdx.x;
  int lane = t & 63;
  int wid = __builtin_amdgcn_readfirstlane(t >> 6);
  int c = blockIdx.x * NPB + wid / WPN;
  if (c >= n_nodes) return;
  c = __builtin_amdgcn_readfirstlane(c);
  int h = wid % WPN;

  int beg = __builtin_amdgcn_readfirstlane(rowptr[c]);
  int end = __builtin_amdgcn_readfirstlane(rowptr[c + 1]);
  float ds = dis[c];

  int fo = h * FPW + lane * VPL;
  const unsigned short* Hl = H + fo;

  // issue self-row + bias loads early (independent of edge metadata)
  uint2 rs;
  union { uint2 v; unsigned short u[4]; } bu;
  if constexpr (VPL == 4) {
    rs = *(const uint2*)(Hl + (size_t)c * F);
    bu.v = *(const uint2*)(bias + fo);
  } else {
    rs.x = *(const uint32_t*)(Hl + (size_t)c * F);
    bu.v.x = *(const uint32_t*)(bias + fo);
  }

  float acc[VPL];
  #pragma unroll
  for (int j = 0; j < VPL; ++j) acc[j] = 0.0f;

  for (int base = beg; base < end; base += 64) {
    int n = end - base;
    if (n > 64) n = 64;
    n = __builtin_amdgcn_readfirstlane(n);
    // one coalesced 8B metadata load per <=64 edges; lanes >= n hold w=0
    int2 mv = make_int2(0, 0);
    if (lane < n) mv = epair[base + lane];
    for (int q0 = 0; q0 < n; q0 += DEPTH) {
      uint2 r[DEPTH];
      float w[DEPTH];
      #pragma unroll
      for (int j = 0; j < DEPTH; ++j) {
        int q = q0 + j;
        int qs = (q < n) ? q : 0;                       // clamp: row sv[0] is L1-hot
        int sq = __builtin_amdgcn_readlane(mv.x, qs);   // SGPR row index
        w[j] = __int_as_float(
            __builtin_amdgcn_readlane(mv.y, q));        // 0 for q>=n
        const unsigned short* src = Hl + (size_t)sq * F;
        if constexpr (VPL == 4) r[j] = *(const uint2*)src;
        else                    r[j].x = *(const uint32_t*)src;
      }
      #pragma unroll
      for (int j = 0; j < DEPTH; ++j) {
        if constexpr (VPL == 4) accum4(acc, r[j], w[j]);
        else                    accum2(acc, r[j].x, w[j]);
      }
    }
  }

  float wself = ds * ds;  // == 1/deg
  if constexpr (VPL == 4) accum4(acc, rs, wself);
  else                    accum2(acc, rs.x, wself);

  float vpost[VPL];
  #pragma unroll
  for (int j = 0; j < VPL; ++j)
    vpost[j] = fmaxf(acc[j] + bf2f(bu.u[j]), 0.0f);

  if constexpr (FUSE_FC) {
    // lane owns features {2*lane, 2*lane+1}; float2 LDS read per output o
    const float2* W2p = (const float2*)Ws;   // [o][k/2] float2
    float part[14];
    #pragma unroll
    for (int o = 0; o < 14; ++o) {
      float2 wv = W2p[o * 64 + lane];
      part[o] = vpost[0] * wv.x + vpost[1] * wv.y;
    }
    #pragma unroll
    for (int off = 32; off; off >>= 1)
      #pragma unroll
      for (int o = 0; o < 14; ++o)
        part[o] += __shfl_xor(part[o], off);
    if (lane == 0) {
      float* op = fcout + (size_t)c * 14;
      #pragma unroll
      for (int o = 0; o < 14; ++o)
        op[o] = 1.0f / (1.0f + __expf(-(part[o] + bs[o])));
    }
  } else {
    unsigned short ob[VPL];
    #pragma unroll
    for (int j = 0; j < VPL; ++j) ob[j] = f2bf(vpost[j]);
    if constexpr (VPL == 4) {
      uint2 st;
      st.x = (uint32_t)ob[0] | ((uint32_t)ob[1] << 16);
      st.y = (uint32_t)ob[2] | ((uint32_t)ob[3] << 16);
      *(uint2*)(Out + (size_t)c * F + fo) = st;
    } else {
      *(uint32_t*)(Out + (size_t)c * F + fo) =
          (uint32_t)ob[0] | ((uint32_t)ob[1] << 16);
    }
  }
}

// ---------- launch ----------
static inline size_t padsz(size_t x) { return (x + 255) & ~(size_t)255; }
static inline void* wsa(char*& p, size_t bytes) {
  void* r = p;
  p += padsz(bytes);
  return r;
}

extern "C" void kernel_launch(void* const* d_in, const int* in_sizes, int n_in,
                              void* d_out, int out_size, void* d_ws, size_t ws_size,
                              hipStream_t stream) {
  const void* Xr   = d_in[0];   // [N,1024] fp32 (probed)
  const void* EIr  = d_in[1];   // [2,E] int64 (probed)
  const void* EWr  = d_in[2];   // [E]
  const void* W1r  = d_in[3];   // [1024,512]
  const void* b1r  = d_in[4];
  const void* W2r  = d_in[5];   // [512,128]
  const void* b2r  = d_in[6];
  const void* Wfcr = d_in[7];   // [128,14]
  const void* bfcr = d_in[8];
  float* out = (float*)d_out;   // [N,14] fp32

  const int N = in_sizes[0] / 1024;   // 50000
  const int E = in_sizes[2];          // 800000

  size_t need = padsz((size_t)N * 512 * 2)          // R1
              + padsz((size_t)N * 1024 * 2)         // R2 (X_bf / X2)
              + 4 * padsz((size_t)N * 4)            // deg, dis, counts, fill
              + padsz((size_t)(N + 1) * 4)
              + padsz(256 * 4)
              + padsz((size_t)E * 8)                // epair
              + padsz(1024 * 512 * 2) + padsz(512 * 128 * 2)
              + padsz(512 * 2) + padsz(128 * 2) + padsz(128 * 14 * 2)
              + padsz(32) + padsz(8);
  const bool big = ws_size >= need;   // constant across calls -> graph-safe

  char* p = (char*)d_ws;
  unsigned short* R1  = (unsigned short*)wsa(p, (size_t)N * 512 * 2);
  unsigned short* R2  = (unsigned short*)wsa(p, (size_t)N * (big ? 1024 : 512) * 2);
  float* deg      = (float*)wsa(p, (size_t)N * 4);
  float* dis      = (float*)wsa(p, (size_t)N * 4);
  int*   counts   = (int*)wsa(p, (size_t)N * 4);
  int*   fill     = (int*)wsa(p, (size_t)N * 4);
  int*   rowptr   = (int*)wsa(p, (size_t)(N + 1) * 4);
  int*   blocksum = (int*)wsa(p, 256 * 4);
  int2*  epair    = (int2*)wsa(p, (size_t)E * 8);
  unsigned short* W1t  = (unsigned short*)wsa(p, (size_t)1024 * 512 * 2);  // [512][1024]
  unsigned short* W2t  = (unsigned short*)wsa(p, (size_t)512 * 128 * 2);   // [128][512]
  unsigned short* b1c  = (unsigned short*)wsa(p, 512 * 2);
  unsigned short* b2c  = (unsigned short*)wsa(p, 128 * 2);
  unsigned short* Wfcc = (unsigned short*)wsa(p, 128 * 14 * 2);
  unsigned short* bfcc = (unsigned short*)wsa(p, 32);
  int* flags      = (int*)wsa(p, 8);

  unsigned short* H1  = R1;                       // [N,512]
  unsigned short* Xbf = R2;                       // [N,1024] (big only)
  unsigned short* X2  = R2;                       // [N,512] — overwrites X_bf (dead)
  unsigned short* H2  = R1;                       // [N,128] — H1 dead

  int gN = (N + 255) / 256;
  int gE = (E + 255) / 256;

  // init (flags-independent) + wave-parallel probe, one kernel
  bgcn_init_probe<<<gN, 256, 0, stream>>>(deg, counts, fill, N,
                                          (const uint32_t*)Xr, (const uint32_t*)EIr, flags);
  // all weight canonicalization in one kernel (W1t, W2t, b1, b2, Wfc, bfc)
  bgcn_cvt_weights<<<586, 256, 0, stream>>>(W1r, W2r, b1r, b2r, Wfcr, bfcr,
                                            W1t, W2t, b1c, b2c, Wfcc, bfcc, flags);
  if (big) {
    int n8 = N * 1024 / 8;
    bgcn_cvt8<<<(n8 + 255) / 256, 256, 0, stream>>>(Xr, Xbf, n8, flags);
  }

  // graph preprocessing (raw ei/ew, one edge pass for deg+hist)
  bgcn_deg_hist<<<gE, 256, 0, stream>>>(EIr, EWr, flags, deg, counts, E);
  int nb = (N + 1023) / 1024;
  bgcn_scan_block<<<nb, 1024, 0, stream>>>(counts, rowptr, blocksum, deg, dis, N);
  bgcn_scan_tops<<<1, 1024, 0, stream>>>(blocksum, nb);
  bgcn_scan_add<<<nb, 1024, 0, stream>>>(rowptr, blocksum, N);
  bgcn_scatter<<<gE, 256, 0, stream>>>(EIr, EWr, flags, dis, rowptr, fill, epair, E);

  int mblks = (N + 127) / 128;   // 391

  // layer 1: H1 = X @ W1 ; X2 = relu(agg(H1) + b1)
  if (big)
    bgcn_gemm_lds<<<mblks * 4, 256, 0, stream>>>(Xbf, W1t, H1, N, 512, 1024, 2);
  else
    bgcn_gemm128<<<mblks * 4, 256, 0, stream>>>(Xr, 1, flags, W1t, H1, N, 512, 1024, 2);
  bgcn_aggregate<512, 2, false><<<(N + 1) / 2, 256, 0, stream>>>(
      H1, rowptr, epair, dis, b1c, X2, nullptr, nullptr, nullptr, N);

  // layer 2: H2 = X2 @ W2 ; out = sigmoid(relu(agg(H2)+b2) @ Wfc + bfc)  [FC fused]
  bgcn_gemm_lds<<<mblks, 256, 0, stream>>>(X2, W2t, H2, N, 128, 512, 0);
  bgcn_aggregate<128, 1, true><<<(N + 3) / 4, 256, 0, stream>>>(
      H2, rowptr, epair, dis, b2c, nullptr, Wfcc, bfcc, out, N);
}

// Round 6
// 690.911 us; speedup vs baseline: 1.0681x; 1.0681x over previous
//
#include <hip/hip_runtime.h>
#include <stdint.h>

// ---------- bf16 helpers (OCP bf16 == high 16 bits of f32) ----------
__device__ __forceinline__ float bf2f(unsigned short h) {
  union { uint32_t u; float f; } v; v.u = ((uint32_t)h) << 16; return v.f;
}
__device__ __forceinline__ unsigned short f2bf(float f) {
  union { float f; uint32_t u; } v; v.f = f;
  uint32_t u = v.u;
  u += 0x7FFFu + ((u >> 16) & 1u);   // round-to-nearest-even
  return (unsigned short)(u >> 16);
}
__device__ __forceinline__ uint32_t pack2bf(float a, float b) {
  return (uint32_t)f2bf(a) | ((uint32_t)f2bf(b) << 16);
}
// raw-dtype readers (probed at runtime)
__device__ __forceinline__ int ld_idx(const void* p, size_t i, int is64) {
  return is64 ? (int)((const long long*)p)[i] : ((const int*)p)[i];
}
__device__ __forceinline__ float ld_w(const void* p, size_t i, int f32) {
  return f32 ? ((const float*)p)[i] : bf2f(((const unsigned short*)p)[i]);
}

typedef __attribute__((ext_vector_type(8))) short short8;   // 8 bf16 (4 VGPRs)
typedef __attribute__((ext_vector_type(4))) float floatx4;  // MFMA C/D

// async global->LDS, 16 B/lane. LDS dest = wave-uniform base + lane*16 (m104/m108).
__device__ __forceinline__ void gl2lds16(const unsigned short* g, unsigned short* l) {
  __builtin_amdgcn_global_load_lds(
      (const __attribute__((address_space(1))) uint32_t*)(const void*)g,
      (__attribute__((address_space(3))) uint32_t*)(void*)l,
      16, 0, 0);
}

// ---------- init + dtype probe (merged; probe is wave-parallel in block 0) ----------
__global__ void bgcn_init_probe(float* __restrict__ deg, int* __restrict__ counts,
                                int* __restrict__ fill, int n,
                                const uint32_t* __restrict__ xw,
                                const uint32_t* __restrict__ iw,
                                int* __restrict__ flags) {
  int i = blockIdx.x * 256 + threadIdx.x;
  if (i < n) { deg[i] = 1.0f; counts[i] = 0; fill[i] = 0; }
  if (blockIdx.x == 0 && threadIdx.x < 64) {
    int lane = threadIdx.x;
    // X dtype heuristic: 256 exponent bytes, 4 per lane (parallel loads)
    int hits = 0;
    #pragma unroll
    for (int j = 0; j < 4; ++j) {
      uint32_t b = (xw[lane * 4 + j] >> 8) & 0x7F;
      hits += (b >= 0x38 && b <= 0x41) ? 1 : 0;
    }
    #pragma unroll
    for (int off = 32; off; off >>= 1) hits += __shfl_xor(hits, off);
    // index dtype: odd 32-bit words 1,3,...,127 all zero => int64
    unsigned long long nz = __ballot(iw[2 * lane + 1] != 0u);
    if (lane == 0) {
      flags[0] = (hits < 128) ? 1 : 0;   // 1 => fp32 floats
      flags[1] = (nz == 0ull) ? 1 : 0;   // 1 => int64 indices
    }
  }
}

// ---------- canonicalization ----------
// X pre-pass, 8 elem/thread
__global__ void bgcn_cvt8(const void* __restrict__ src, unsigned short* __restrict__ dst,
                          int n8, const int* __restrict__ flags) {
  int i = blockIdx.x * 256 + threadIdx.x;
  if (i >= n8) return;
  size_t o = (size_t)i * 8;
  uint4 d;
  if (flags[0]) {
    const float4* f = (const float4*)((const float*)src + o);
    float4 f0 = f[0], f1 = f[1];
    d = make_uint4(pack2bf(f0.x, f0.y), pack2bf(f0.z, f0.w),
                   pack2bf(f1.x, f1.y), pack2bf(f1.z, f1.w));
  } else {
    d = *(const uint4*)((const unsigned short*)src + o);
  }
  *(uint4*)(dst + o) = d;
}
// LDS-tiled transpose+cvt: dst[N][K] bf16 <- src[K][N]. K,N multiples of 32.
__global__ __launch_bounds__(256) void bgcn_cvt_t(
    const void* __restrict__ src, unsigned short* __restrict__ dst,
    int K, int N, const int* __restrict__ flags) {
  __shared__ unsigned short tile[32][33];
  int k0 = blockIdx.x * 32, n0 = blockIdx.y * 32;
  int tx = threadIdx.x & 31, ty = threadIdx.x >> 5;   // ty 0..7
  bool f32 = flags[0];
  #pragma unroll
  for (int i = 0; i < 4; ++i) {
    size_t s = (size_t)(k0 + ty + i * 8) * N + n0 + tx;
    tile[ty + i * 8][tx] = f32 ? f2bf(((const float*)src)[s])
                               : ((const unsigned short*)src)[s];
  }
  __syncthreads();
  #pragma unroll
  for (int i = 0; i < 4; ++i)
    dst[(size_t)(n0 + ty + i * 8) * K + k0 + tx] = tile[tx][ty + i * 8];
}
// fused small-weight cvt: b1(512) b2(128) Wfc(1792) bfc(14)
__global__ void bgcn_cvt_small(const void* b1, const void* b2,
                               const void* wfc, const void* bfc,
                               unsigned short* db1, unsigned short* db2,
                               unsigned short* dwfc, unsigned short* dbfc,
                               const int* __restrict__ flags) {
  int i = blockIdx.x * 256 + threadIdx.x;
  bool f32 = flags[0];
  const void* s; unsigned short* d; int j;
  if (i < 512)            { s = b1;  d = db1;  j = i; }
  else if (i < 640)       { s = b2;  d = db2;  j = i - 512; }
  else if (i < 2432)      { s = wfc; d = dwfc; j = i - 640; }
  else if (i < 2446)      { s = bfc; d = dbfc; j = i - 2432; }
  else return;
  d[j] = f32 ? f2bf(((const float*)s)[j]) : ((const unsigned short*)s)[j];
}

// ---------- graph preprocessing ----------
__global__ void bgcn_deg_hist(const void* __restrict__ ei, const void* __restrict__ ew,
                              const int* __restrict__ flags,
                              float* __restrict__ deg, int* __restrict__ counts, int E) {
  int e = blockIdx.x * 256 + threadIdx.x;
  if (e >= E) return;
  int c = ld_idx(ei, (size_t)E + e, flags[1]);
  atomicAdd(&deg[c], ld_w(ew, e, flags[0]));
  atomicAdd(&counts[c], 1);
}
// block scan over counts -> rowptr (inclusive partials); also finalizes dis
__global__ void bgcn_scan_block(const int* __restrict__ counts, int* __restrict__ rowptr,
                                int* __restrict__ blocksum,
                                const float* __restrict__ deg, float* __restrict__ dis,
                                int n) {
  __shared__ int buf[1024];
  int gid = blockIdx.x * 1024 + threadIdx.x;
  int v = (gid < n) ? counts[gid] : 0;
  buf[threadIdx.x] = v;
  __syncthreads();
  for (int off = 1; off < 1024; off <<= 1) {
    int x = (threadIdx.x >= off) ? buf[threadIdx.x - off] : 0;
    __syncthreads();
    buf[threadIdx.x] += x;
    __syncthreads();
  }
  if (gid < n) {
    rowptr[gid + 1] = buf[threadIdx.x];
    dis[gid] = rsqrtf(deg[gid]);   // deg final here (after deg_hist)
  }
  if (threadIdx.x == 1023) blocksum[blockIdx.x] = buf[1023];
}
// block-parallel exclusive scan of blocksum (nb <= 1024)
__global__ void bgcn_scan_tops(int* __restrict__ blocksum, int nb) {
  __shared__ int buf[1024];
  int t = threadIdx.x;
  int v = (t < nb) ? blocksum[t] : 0;
  buf[t] = v;
  __syncthreads();
  for (int off = 1; off < 1024; off <<= 1) {
    int x = (t >= off) ? buf[t - off] : 0;
    __syncthreads();
    buf[t] += x;
    __syncthreads();
  }
  if (t < nb) blocksum[t] = buf[t] - v;   // exclusive
}
__global__ void bgcn_scan_add(int* __restrict__ rowptr, const int* __restrict__ blocksum, int n) {
  int gid = blockIdx.x * 1024 + threadIdx.x;
  if (gid < n) rowptr[gid + 1] += blocksum[blockIdx.x];
  if (gid == 0) rowptr[0] = 0;
}
// scatter into CSR; (src, norm) packed as one int2 -> single 8B scattered store
__global__ void bgcn_scatter(const void* __restrict__ ei, const void* __restrict__ ew,
                             const int* __restrict__ flags,
                             const float* __restrict__ dis,
                             const int* __restrict__ rowptr, int* __restrict__ fill,
                             int2* __restrict__ epair, int E) {
  int e = blockIdx.x * 256 + threadIdx.x;
  if (e >= E) return;
  int is64 = flags[1];
  int r = ld_idx(ei, e, is64), c = ld_idx(ei, (size_t)E + e, is64);
  int pos = rowptr[c] + atomicAdd(&fill[c], 1);
  float nrm = dis[r] * ld_w(ew, e, flags[0]) * dis[c];
  epair[pos] = make_int2(r, __float_as_int(nrm));
}

// ---------- m97-style MFMA GEMM (bf16 A): C[MxN] = A[MxK] @ Bt[NxK]^T ----------
__global__ __launch_bounds__(256) void bgcn_gemm_lds(
    const unsigned short* __restrict__ A,
    const unsigned short* __restrict__ Bt,
    unsigned short* __restrict__ C,
    int M, int N, int K, int nblk_bits) {
  __shared__ unsigned short Abuf[128 * 32];
  __shared__ unsigned short Bbuf[128 * 32];
  int t = threadIdx.x;
  int wave = t >> 6, lane = t & 63;
  int bx = blockIdx.x;
  int nblk = bx & ((1 << nblk_bits) - 1);
  int mblk = bx >> nblk_bits;
  int m0 = mblk * 128, n0 = nblk * 128;

  floatx4 acc[4][4];
  #pragma unroll
  for (int i = 0; i < 4; ++i)
    #pragma unroll
    for (int j = 0; j < 4; ++j)
      #pragma unroll
      for (int r = 0; r < 4; ++r) acc[i][j][r] = 0.0f;

  int rii  = lane >> 2;
  int koff = (lane & 3) * 8;
  int ar0 = m0 + wave * 32 + rii;      if (ar0 >= M) ar0 = M - 1;
  int ar1 = m0 + wave * 32 + 16 + rii; if (ar1 >= M) ar1 = M - 1;
  const unsigned short* Ag0 = A + (size_t)ar0 * K + koff;
  const unsigned short* Ag1 = A + (size_t)ar1 * K + koff;
  const unsigned short* Bg0 = Bt + (size_t)(n0 + wave * 32 + rii) * K + koff;
  const unsigned short* Bg1 = Bg0 + (size_t)16 * K;
  unsigned short* Al0 = Abuf + (wave * 32) * 32 + lane * 8;
  unsigned short* Al1 = Abuf + (wave * 32 + 16) * 32 + lane * 8;
  unsigned short* Bl0 = Bbuf + (wave * 32) * 32 + lane * 8;
  unsigned short* Bl1 = Bbuf + (wave * 32 + 16) * 32 + lane * 8;

  int fr = lane & 15;
  int fk = (lane >> 4) * 8;
  int mw = (wave & 1) * 64;
  int nw = (wave >> 1) * 64;

  for (int k0 = 0; k0 < K; k0 += 32) {
    gl2lds16(Ag0 + k0, Al0);
    gl2lds16(Ag1 + k0, Al1);
    gl2lds16(Bg0 + k0, Bl0);
    gl2lds16(Bg1 + k0, Bl1);
    __syncthreads();

    short8 afr[4], bfr[4];
    #pragma unroll
    for (int i = 0; i < 4; ++i)
      afr[i] = *(const short8*)(Abuf + (mw + i * 16 + fr) * 32 + fk);
    #pragma unroll
    for (int i = 0; i < 4; ++i)
      bfr[i] = *(const short8*)(Bbuf + (nw + i * 16 + fr) * 32 + fk);
    #pragma unroll
    for (int mt = 0; mt < 4; ++mt)
      #pragma unroll
      for (int nt = 0; nt < 4; ++nt)
        acc[mt][nt] = __builtin_amdgcn_mfma_f32_16x16x32_bf16(afr[mt], bfr[nt], acc[mt][nt], 0, 0, 0);
    __syncthreads();
  }

  int col_l = lane & 15;
  int row_b = (lane >> 4) * 4;
  #pragma unroll
  for (int mt = 0; mt < 4; ++mt)
    #pragma unroll
    for (int nt = 0; nt < 4; ++nt)
      #pragma unroll
      for (int r = 0; r < 4; ++r) {
        int m = m0 + mw + mt * 16 + row_b + r;
        if (m < M)
          C[(size_t)m * N + n0 + nw + nt * 16 + col_l] = f2bf(acc[mt][nt][r]);
      }
}

// ---------- fallback GEMM (fp32-or-bf16 A via VGPR staging) ----------
#define GST 40
__global__ __launch_bounds__(256, 2) void bgcn_gemm128(
    const void* __restrict__ Araw, int a_probe, const int* __restrict__ flags,
    const unsigned short* __restrict__ Bt,
    unsigned short* __restrict__ C,
    int M, int N, int K, int nblk_bits) {
  __shared__ unsigned short Abuf[128 * GST];
  __shared__ unsigned short Bbuf[128 * GST];
  const bool a_fp32 = a_probe && flags[0];
  int t = threadIdx.x;
  int wave = t >> 6, lane = t & 63;
  int bx = blockIdx.x;
  int nblk = bx & ((1 << nblk_bits) - 1);
  int mblk = bx >> nblk_bits;
  int m0 = mblk * 128, n0 = nblk * 128;

  floatx4 acc[4][4];
  #pragma unroll
  for (int i = 0; i < 4; ++i)
    #pragma unroll
    for (int j = 0; j < 4; ++j)
      #pragma unroll
      for (int r = 0; r < 4; ++r) acc[i][j][r] = 0.0f;

  int srow  = t >> 1;
  int skoff = (t & 1) * 16;
  int am = m0 + srow; if (am >= M) am = M - 1;
  const float*          Af = (const float*)Araw          + (size_t)am * K + skoff;
  const unsigned short* Ah = (const unsigned short*)Araw + (size_t)am * K + skoff;
  const unsigned short* Bp = Bt + (size_t)(n0 + srow) * K + skoff;
  unsigned short* AL = Abuf + srow * GST + skoff;
  unsigned short* BL = Bbuf + srow * GST + skoff;

  int fr = lane & 15;
  int fk = (lane >> 4) * 8;
  int mw = (wave & 1) * 64;
  int nw = (wave >> 1) * 64;

  for (int k0 = 0; k0 < K; k0 += 32) {
    uint4 a0, a1;
    if (a_fp32) {
      float4 f0 = *(const float4*)(Af + k0);
      float4 f1 = *(const float4*)(Af + k0 + 4);
      float4 f2 = *(const float4*)(Af + k0 + 8);
      float4 f3 = *(const float4*)(Af + k0 + 12);
      a0 = make_uint4(pack2bf(f0.x, f0.y), pack2bf(f0.z, f0.w),
                      pack2bf(f1.x, f1.y), pack2bf(f1.z, f1.w));
      a1 = make_uint4(pack2bf(f2.x, f2.y), pack2bf(f2.z, f2.w),
                      pack2bf(f3.x, f3.y), pack2bf(f3.z, f3.w));
    } else {
      a0 = *(const uint4*)(Ah + k0);
      a1 = *(const uint4*)(Ah + k0 + 8);
    }
    uint4 b0 = *(const uint4*)(Bp + k0);
    uint4 b1 = *(const uint4*)(Bp + k0 + 8);
    *(uint4*)AL       = a0;
    *(uint4*)(AL + 8) = a1;
    *(uint4*)BL       = b0;
    *(uint4*)(BL + 8) = b1;
    __syncthreads();

    short8 afr[4], bfr[4];
    #pragma unroll
    for (int i = 0; i < 4; ++i)
      afr[i] = *(const short8*)(Abuf + (mw + i * 16 + fr) * GST + fk);
    #pragma unroll
    for (int i = 0; i < 4; ++i)
      bfr[i] = *(const short8*)(Bbuf + (nw + i * 16 + fr) * GST + fk);
    #pragma unroll
    for (int mt = 0; mt < 4; ++mt)
      #pragma unroll
      for (int nt = 0; nt < 4; ++nt)
        acc[mt][nt] = __builtin_amdgcn_mfma_f32_16x16x32_bf16(afr[mt], bfr[nt], acc[mt][nt], 0, 0, 0);
    __syncthreads();
  }

  int col_l = lane & 15;
  int row_b = (lane >> 4) * 4;
  #pragma unroll
  for (int mt = 0; mt < 4; ++mt)
    #pragma unroll
    for (int nt = 0; nt < 4; ++nt)
      #pragma unroll
      for (int r = 0; r < 4; ++r) {
        int m = m0 + mw + mt * 16 + row_b + r;
        if (m < M)
          C[(size_t)m * N + n0 + nw + nt * 16 + col_l] = f2bf(acc[mt][nt][r]);
      }
}

// ---------- aggregation: out[c] = sum_e norm*H[src] + (1/deg_c)*H[c] + b, relu ----------
// Column-sliced across XCDs: a block only touches a fixed 128-col slice of H
// (slice = blockIdx.x & (SLICES-1); with round-robin XCD = blockIdx.x % 8 each
// XCD caches only table_size/SLICES of H -> much higher L2 hit rate on the
// ~E/N-touch row reuse). FPW = F/SLICES = 128 for both instantiations ->
// single uint32-gather code path. DEPTH=8 keeps VGPR under the 64 step.
__device__ __forceinline__ void accum2(float* acc, uint32_t r, float w) {
  acc[0] += w * bf2f((unsigned short)(r & 0xffff));
  acc[1] += w * bf2f((unsigned short)(r >> 16));
}

template <int F, int SLICES>
__global__ __launch_bounds__(256) void bgcn_aggregate(
    const unsigned short* __restrict__ H,
    const int* __restrict__ rowptr,
    const int2* __restrict__ epair,
    const float* __restrict__ dis,
    const unsigned short* __restrict__ bias,
    unsigned short* __restrict__ Out,
    int n_nodes) {
  constexpr int FPW = F / SLICES;  // 128
  constexpr int VPL = FPW / 64;    // 2
  constexpr int SB = (SLICES == 4) ? 2 : (SLICES == 2) ? 1 : 0;
  constexpr int DEPTH = 8;         // gather loads in flight

  int t = threadIdx.x;
  int lane = t & 63;
  int wid = __builtin_amdgcn_readfirstlane(t >> 6);
  int s = blockIdx.x & (SLICES - 1);        // column slice (XCD-aligned)
  int c = (blockIdx.x >> SB) * 4 + wid;     // one wave per node
  if (c >= n_nodes) return;
  c = __builtin_amdgcn_readfirstlane(c);

  int beg = __builtin_amdgcn_readfirstlane(rowptr[c]);
  int end = __builtin_amdgcn_readfirstlane(rowptr[c + 1]);
  float ds = dis[c];

  int fo = s * FPW + lane * VPL;
  const unsigned short* Hl = H + fo;

  // issue self-row + bias loads early (independent of edge metadata)
  uint32_t rs = *(const uint32_t*)(Hl + (size_t)c * F);
  uint32_t buv = *(const uint32_t*)(bias + fo);

  float acc[VPL];
  #pragma unroll
  for (int j = 0; j < VPL; ++j) acc[j] = 0.0f;

  for (int base = beg; base < end; base += 64) {
    int n = end - base;
    if (n > 64) n = 64;
    n = __builtin_amdgcn_readfirstlane(n);
    // one coalesced 8B metadata load per <=64 edges; lanes >= n hold w=0
    int2 mv = make_int2(0, 0);
    if (lane < n) mv = epair[base + lane];
    for (int q0 = 0; q0 < n; q0 += DEPTH) {
      uint32_t r[DEPTH];
      float w[DEPTH];
      #pragma unroll
      for (int j = 0; j < DEPTH; ++j) {
        int q = q0 + j;
        int qs = (q < n) ? q : 0;                       // clamp: row sv[0] is L1-hot
        int sq = __builtin_amdgcn_readlane(mv.x, qs);   // SGPR row index
        w[j] = __int_as_float(
            __builtin_amdgcn_readlane(mv.y, q));        // 0 for q>=n
        r[j] = *(const uint32_t*)(Hl + (size_t)sq * F);
      }
      #pragma unroll
      for (int j = 0; j < DEPTH; ++j) accum2(acc, r[j], w[j]);
    }
  }

  float wself = ds * ds;  // == 1/deg
  accum2(acc, rs, wself);

  unsigned short ob[VPL];
  #pragma unroll
  for (int j = 0; j < VPL; ++j) {
    float v = acc[j] + bf2f((unsigned short)((buv >> (16 * j)) & 0xffff));
    ob[j] = f2bf(fmaxf(v, 0.0f));
  }
  *(uint32_t*)(Out + (size_t)c * F + fo) =
      (uint32_t)ob[0] | ((uint32_t)ob[1] << 16);
}

// ---------- FC(128->14) + sigmoid -> FP32 output ----------
__global__ __launch_bounds__(256) void bgcn_fc_sigmoid(
    const unsigned short* __restrict__ X,
    const unsigned short* __restrict__ W,
    const unsigned short* __restrict__ b,
    float* __restrict__ out,
    int n_nodes) {
  __shared__ float Ws[128 * 14];
  __shared__ float bs[14];
  for (int i = threadIdx.x; i < 128 * 14; i += 256) Ws[i] = bf2f(W[i]);
  if (threadIdx.x < 14) bs[threadIdx.x] = bf2f(b[threadIdx.x]);
  __syncthreads();
  int node = blockIdx.x * 256 + threadIdx.x;
  if (node >= n_nodes) return;
  float acc[14];
  #pragma unroll
  for (int c = 0; c < 14; ++c) acc[c] = bs[c];
  const unsigned short* xp = X + (size_t)node * 128;
  for (int k8 = 0; k8 < 16; ++k8) {
    uint4 r = *(const uint4*)(xp + k8 * 8);
    float xv[8];
    xv[0] = bf2f((unsigned short)(r.x & 0xffff)); xv[1] = bf2f((unsigned short)(r.x >> 16));
    xv[2] = bf2f((unsigned short)(r.y & 0xffff)); xv[3] = bf2f((unsigned short)(r.y >> 16));
    xv[4] = bf2f((unsigned short)(r.z & 0xffff)); xv[5] = bf2f((unsigned short)(r.z >> 16));
    xv[6] = bf2f((unsigned short)(r.w & 0xffff)); xv[7] = bf2f((unsigned short)(r.w >> 16));
    #pragma unroll
    for (int j = 0; j < 8; ++j) {
      int k = k8 * 8 + j;
      #pragma unroll
      for (int c = 0; c < 14; ++c) acc[c] = fmaf(xv[j], Ws[k * 14 + c], acc[c]);
    }
  }
  float* op = out + (size_t)node * 14;
  #pragma unroll
  for (int c = 0; c < 14; ++c)
    op[c] = 1.0f / (1.0f + __expf(-acc[c]));
}

// ---------- launch ----------
static inline size_t padsz(size_t x) { return (x + 255) & ~(size_t)255; }
static inline void* wsa(char*& p, size_t bytes) {
  void* r = p;
  p += padsz(bytes);
  return r;
}

extern "C" void kernel_launch(void* const* d_in, const int* in_sizes, int n_in,
                              void* d_out, int out_size, void* d_ws, size_t ws_size,
                              hipStream_t stream) {
  const void* Xr   = d_in[0];   // [N,1024] fp32 (probed)
  const void* EIr  = d_in[1];   // [2,E] int64 (probed)
  const void* EWr  = d_in[2];   // [E]
  const void* W1r  = d_in[3];   // [1024,512]
  const void* b1r  = d_in[4];
  const void* W2r  = d_in[5];   // [512,128]
  const void* b2r  = d_in[6];
  const void* Wfcr = d_in[7];   // [128,14]
  const void* bfcr = d_in[8];
  float* out = (float*)d_out;   // [N,14] fp32

  const int N = in_sizes[0] / 1024;   // 50000
  const int E = in_sizes[2];          // 800000

  size_t need = padsz((size_t)N * 512 * 2)          // R1
              + padsz((size_t)N * 1024 * 2)         // R2 (X_bf / X2)
              + 4 * padsz((size_t)N * 4)            // deg, dis, counts, fill
              + padsz((size_t)(N + 1) * 4)
              + padsz(256 * 4)
              + padsz((size_t)E * 8)                // epair
              + padsz(1024 * 512 * 2) + padsz(512 * 128 * 2)
              + padsz(512 * 2) + padsz(128 * 2) + padsz(128 * 14 * 2)
              + padsz(32) + padsz(8);
  const bool big = ws_size >= need;   // constant across calls -> graph-safe

  char* p = (char*)d_ws;
  unsigned short* R1  = (unsigned short*)wsa(p, (size_t)N * 512 * 2);
  unsigned short* R2  = (unsigned short*)wsa(p, (size_t)N * (big ? 1024 : 512) * 2);
  float* deg      = (float*)wsa(p, (size_t)N * 4);
  float* dis      = (float*)wsa(p, (size_t)N * 4);
  int*   counts   = (int*)wsa(p, (size_t)N * 4);
  int*   fill     = (int*)wsa(p, (size_t)N * 4);
  int*   rowptr   = (int*)wsa(p, (size_t)(N + 1) * 4);
  int*   blocksum = (int*)wsa(p, 256 * 4);
  int2*  epair    = (int2*)wsa(p, (size_t)E * 8);
  unsigned short* W1t  = (unsigned short*)wsa(p, (size_t)1024 * 512 * 2);  // [512][1024]
  unsigned short* W2t  = (unsigned short*)wsa(p, (size_t)512 * 128 * 2);   // [128][512]
  unsigned short* b1c  = (unsigned short*)wsa(p, 512 * 2);
  unsigned short* b2c  = (unsigned short*)wsa(p, 128 * 2);
  unsigned short* Wfcc = (unsigned short*)wsa(p, 128 * 14 * 2);
  unsigned short* bfcc = (unsigned short*)wsa(p, 32);
  int* flags      = (int*)wsa(p, 8);

  unsigned short* H1  = R1;                       // [N,512]
  unsigned short* Xbf = R2;                       // [N,1024] (big only)
  unsigned short* X2  = R2;                       // [N,512] — overwrites X_bf (dead)
  unsigned short* H2  = R1;                       // [N,128] — H1 dead
  unsigned short* X3  = R1 + (size_t)N * 128;     // [N,128] — disjoint from H2

  int gN = (N + 255) / 256;
  int gE = (E + 255) / 256;

  // init (flags-independent) + wave-parallel probe, one kernel
  bgcn_init_probe<<<gN, 256, 0, stream>>>(deg, counts, fill, N,
                                          (const uint32_t*)Xr, (const uint32_t*)EIr, flags);
  { dim3 g(1024 / 32, 512 / 32); bgcn_cvt_t<<<g, 256, 0, stream>>>(W1r, W1t, 1024, 512, flags); }
  { dim3 g(512 / 32, 128 / 32);  bgcn_cvt_t<<<g, 256, 0, stream>>>(W2r, W2t, 512, 128, flags); }
  bgcn_cvt_small<<<10, 256, 0, stream>>>(b1r, b2r, Wfcr, bfcr, b1c, b2c, Wfcc, bfcc, flags);
  if (big) {
    int n8 = N * 1024 / 8;
    bgcn_cvt8<<<(n8 + 255) / 256, 256, 0, stream>>>(Xr, Xbf, n8, flags);
  }

  // graph preprocessing (raw ei/ew, one edge pass for deg+hist)
  bgcn_deg_hist<<<gE, 256, 0, stream>>>(EIr, EWr, flags, deg, counts, E);
  int nb = (N + 1023) / 1024;
  bgcn_scan_block<<<nb, 1024, 0, stream>>>(counts, rowptr, blocksum, deg, dis, N);
  bgcn_scan_tops<<<1, 1024, 0, stream>>>(blocksum, nb);
  bgcn_scan_add<<<nb, 1024, 0, stream>>>(rowptr, blocksum, N);
  bgcn_scatter<<<gE, 256, 0, stream>>>(EIr, EWr, flags, dis, rowptr, fill, epair, E);

  int mblks = (N + 127) / 128;   // 391
  int ngrp  = (N + 3) / 4;       // node groups of 4 (one wave per node)

  // layer 1: H1 = X @ W1 ; X2 = relu(agg(H1) + b1)   [4 column slices]
  if (big)
    bgcn_gemm_lds<<<mblks * 4, 256, 0, stream>>>(Xbf, W1t, H1, N, 512, 1024, 2);
  else
    bgcn_gemm128<<<mblks * 4, 256, 0, stream>>>(Xr, 1, flags, W1t, H1, N, 512, 1024, 2);
  bgcn_aggregate<512, 4><<<ngrp * 4, 256, 0, stream>>>(
      H1, rowptr, epair, dis, b1c, X2, N);

  // layer 2: H2 = X2 @ W2 ; X3 = relu(agg(H2) + b2)
  bgcn_gemm_lds<<<mblks, 256, 0, stream>>>(X2, W2t, H2, N, 128, 512, 0);
  bgcn_aggregate<128, 1><<<ngrp, 256, 0, stream>>>(
      H2, rowptr, epair, dis, b2c, X3, N);

  // FC + sigmoid (fp32 out)
  bgcn_fc_sigmoid<<<gN, 256, 0, stream>>>(X3, Wfcc, bfcc, out, N);
}